// Round 2
// baseline (499.183 us; speedup 1.0000x reference)
//
#include <hip/hip_runtime.h>
#include <math.h>

#define NROWS 8192
#define DIMS 64
#define NUM_BW 10

#define BM 128
#define BN 128
#define TM 8
#define TN 8
#define LDK 36   // 32 floats per K-half + 4 pad (keeps b128 alignment, breaks bank aliasing)

struct BwConsts { float e[NUM_BW]; };

__device__ __forceinline__ float fast_exp2(float x) {
#if __has_builtin(__builtin_amdgcn_exp2f)
    return __builtin_amdgcn_exp2f(x);
#else
    return exp2f(x);
#endif
}

// One wave per row: log_softmax + row squared-norm (fp64 reduce for the norm).
__global__ __launch_bounds__(256) void lsm_norm_kernel(
    const float* __restrict__ in, float* __restrict__ out, float* __restrict__ norms)
{
    int wave = threadIdx.x >> 6;
    int lane = threadIdx.x & 63;
    int row = blockIdx.x * 4 + wave;
    float v = in[row * DIMS + lane];
    float m = v;
#pragma unroll
    for (int off = 32; off >= 1; off >>= 1)
        m = fmaxf(m, __shfl_xor(m, off));
    float e = expf(v - m);
    float s = e;
#pragma unroll
    for (int off = 32; off >= 1; off >>= 1)
        s += __shfl_xor(s, off);
    float lse = m + logf(s);
    float o = v - lse;
    out[row * DIMS + lane] = o;
    double q = (double)o * (double)o;
#pragma unroll
    for (int off = 32; off >= 1; off >>= 1)
        q += __shfl_xor(q, off);
    if (lane == 0) norms[row] = (float)q;
}

// z=0: XX (w=1/2, upper triangle), z=1: YY, z=2: XY (w=-2, full).
__global__ __launch_bounds__(256, 2) void pair_kernel(
    const float* __restrict__ X, const float* __restrict__ Y,
    const float* __restrict__ AA, const float* __restrict__ BB,
    BwConsts bc, double* __restrict__ acc_out)
{
    const int z = blockIdx.z;
    const int bi = blockIdx.x, bj = blockIdx.y;
    double w;
    const float *A, *B, *aa, *bb;
    if (z == 0)      { A = X; B = X; aa = AA; bb = AA; }
    else if (z == 1) { A = Y; B = Y; aa = BB; bb = BB; }
    else             { A = X; B = Y; aa = AA; bb = BB; }
    if (z < 2) {
        if (bj < bi) return;               // symmetric: skip lower triangle
        w = (bj == bi) ? 1.0 : 2.0;
    } else {
        w = -2.0;
    }

    __shared__ float As[BM][LDK];
    __shared__ float Bs[BN][LDK];
    __shared__ double wsum[4];

    const int tid = threadIdx.x;
    const int tr = tid >> 4;      // 0..15
    const int tc = tid & 15;      // 0..15
    const int i0 = bi * BM, j0 = bj * BN;

    float accv[TM][TN];
#pragma unroll
    for (int a = 0; a < TM; ++a)
#pragma unroll
        for (int b = 0; b < TN; ++b) accv[a][b] = 0.f;

    for (int kh = 0; kh < DIMS; kh += 32) {
        __syncthreads();
#pragma unroll
        for (int p = 0; p < 4; ++p) {
            int idx = tid + p * 256;       // 0..1023 = 128 rows x 8 float4
            int row = idx >> 3;
            int kc  = (idx & 7) << 2;
            *reinterpret_cast<float4*>(&As[row][kc]) =
                *reinterpret_cast<const float4*>(&A[(size_t)(i0 + row) * DIMS + kh + kc]);
            *reinterpret_cast<float4*>(&Bs[row][kc]) =
                *reinterpret_cast<const float4*>(&B[(size_t)(j0 + row) * DIMS + kh + kc]);
        }
        __syncthreads();
#pragma unroll
        for (int kg = 0; kg < 32; kg += 4) {
            float4 a4[TM], b4[TN];
#pragma unroll
            for (int mi = 0; mi < TM; ++mi)
                a4[mi] = *reinterpret_cast<const float4*>(&As[mi * 16 + tr][kg]);
#pragma unroll
            for (int mj = 0; mj < TN; ++mj)
                b4[mj] = *reinterpret_cast<const float4*>(&Bs[mj * 16 + tc][kg]);
#pragma unroll
            for (int mi = 0; mi < TM; ++mi)
#pragma unroll
                for (int mj = 0; mj < TN; ++mj) {
                    float t = accv[mi][mj];
                    t = fmaf(a4[mi].x, b4[mj].x, t);
                    t = fmaf(a4[mi].y, b4[mj].y, t);
                    t = fmaf(a4[mi].z, b4[mj].z, t);
                    t = fmaf(a4[mi].w, b4[mj].w, t);
                    accv[mi][mj] = t;
                }
        }
    }

    float av[TM], bv[TN];
#pragma unroll
    for (int mi = 0; mi < TM; ++mi) av[mi] = aa[i0 + mi * 16 + tr];
#pragma unroll
    for (int mj = 0; mj < TN; ++mj) bv[mj] = bb[j0 + mj * 16 + tc];

    double th = 0.0;
#pragma unroll
    for (int mi = 0; mi < TM; ++mi)
#pragma unroll
        for (int mj = 0; mj < TN; ++mj) {
            float d = av[mi] + bv[mj] - 2.0f * accv[mi][mj];
            float s = 0.f;
#pragma unroll
            for (int k = 0; k < NUM_BW; ++k)
                s += fast_exp2(d * bc.e[k]);   // exp(-c_k d) = 2^(d * e_k), e_k = -c_k*log2(e)
            th += (double)s;
        }

#pragma unroll
    for (int off = 32; off >= 1; off >>= 1)
        th += __shfl_xor(th, off);
    if ((tid & 63) == 0) wsum[tid >> 6] = th;
    __syncthreads();
    if (tid == 0) {
        double t = (wsum[0] + wsum[1]) + (wsum[2] + wsum[3]);
        atomicAdd(acc_out, w * t);
    }
}

__global__ void finalize_kernel(const double* __restrict__ acc, float* __restrict__ out)
{
    out[0] = (float)(acc[0] / ((double)NROWS * (double)NROWS * (double)NUM_BW));
}

extern "C" void kernel_launch(void* const* d_in, const int* in_sizes, int n_in,
                              void* d_out, int out_size, void* d_ws, size_t ws_size,
                              hipStream_t stream)
{
    const float* src = (const float*)d_in[0];
    const float* tgt = (const float*)d_in[1];
    float* out = (float*)d_out;

    char* ws = (char*)d_ws;
    float* x_ls = (float*)ws;                       // 8192*64 f32 = 2 MB
    float* y_ls = x_ls + (size_t)NROWS * DIMS;      // 2 MB
    float* aa   = y_ls + (size_t)NROWS * DIMS;      // 32 KB
    float* bb   = aa + NROWS;                       // 32 KB
    double* acc = (double*)(bb + NROWS);            // 8 B, 8-aligned

    hipMemsetAsync(acc, 0, sizeof(double), stream);

    lsm_norm_kernel<<<NROWS / 4, 256, 0, stream>>>(src, x_ls, aa);
    lsm_norm_kernel<<<NROWS / 4, 256, 0, stream>>>(tgt, y_ls, bb);

    BwConsts bc;
    const double LOG2E = 1.4426950408889634;
    for (int k = 0; k < NUM_BW; ++k) {
        double bw = pow(128.0, (double)k / 9.0);    // logspace(0, log10(128), 10)
        bc.e[k] = (float)(-(0.5 / (bw * bw)) * LOG2E);
    }

    dim3 grid(NROWS / BM, NROWS / BN, 3);
    pair_kernel<<<grid, 256, 0, stream>>>(x_ls, y_ls, aa, bb, bc, acc);
    finalize_kernel<<<1, 1, 0, stream>>>(acc, out);
}